// Round 12
// baseline (381.288 us; speedup 1.0000x reference)
//
#include <hip/hip_runtime.h>
#include <hip/hip_cooperative_groups.h>

namespace cg = cooperative_groups;

// B=8192, T=240, C=16, DAYS=STRIDE=10 -> W=24 windows tiling T exactly.
// Row r reads contiguous x[r*160 .. r*160+159]. 320 output channels:
// [corr(120), cov(120), std(16), zscore(16), ret(16), decay(16), mean(16)].
#define NROWS   196608
#define NTILES_TOTAL 12288    // 196608 rows / 16 rows-per-tile
#define OUTC    320
#define R_      16            // rows per LDS tile
#define WSTRIDE 164           // win LDS row stride (floats), float4-aligned
#define CV_S    20            // cv2 [pair][row] stride (floats), 16B-aligned
#define FB_S    20            // featB [chan][row] stride (floats), 16B-aligned
#define EPS_F   1e-8f
#define EPS_BN  1e-5f
#define RA_BLOCKS 768         // stage-A reduce grid (fallback path)

// p(i,j) for i<j, row-major triu: p = i*15 - i(i-1)/2 + j - i - 1
__device__ __forceinline__ int pair_idx(int i, int j) {
    return i * 15 - (i * (i - 1)) / 2 + j - i - 1;
}

// pair p -> packed (i<<4)|j for triu_indices(16, k=1), row-major
__device__ const unsigned char PIJ[120] = {
    0x01,0x02,0x03,0x04,0x05,0x06,0x07,0x08,0x09,0x0A,0x0B,0x0C,0x0D,0x0E,0x0F,
    0x12,0x13,0x14,0x15,0x16,0x17,0x18,0x19,0x1A,0x1B,0x1C,0x1D,0x1E,0x1F,
    0x23,0x24,0x25,0x26,0x27,0x28,0x29,0x2A,0x2B,0x2C,0x2D,0x2E,0x2F,
    0x34,0x35,0x36,0x37,0x38,0x39,0x3A,0x3B,0x3C,0x3D,0x3E,0x3F,
    0x45,0x46,0x47,0x48,0x49,0x4A,0x4B,0x4C,0x4D,0x4E,0x4F,
    0x56,0x57,0x58,0x59,0x5A,0x5B,0x5C,0x5D,0x5E,0x5F,
    0x67,0x68,0x69,0x6A,0x6B,0x6C,0x6D,0x6E,0x6F,
    0x78,0x79,0x7A,0x7B,0x7C,0x7D,0x7E,0x7F,
    0x89,0x8A,0x8B,0x8C,0x8D,0x8E,0x8F,
    0x9A,0x9B,0x9C,0x9D,0x9E,0x9F,
    0xAB,0xAC,0xAD,0xAE,0xAF,
    0xBC,0xBD,0xBE,0xBF,
    0xCD,0xCE,0xCF,
    0xDE,0xDF,
    0xEF
};

// ============================================================
// Fused cooperative kernel: stats -> finalize -> apply.
// 320 threads/block (5 waves). Thread t owns OUTPUT CHANNEL t.
// Phase 2 layout = round-7 proven (wave-uniform roles):
//   t in [0,160): Gram register blocks; t in [256,320): scalar families.
// Register prefetch (pf0/pf1) hides staging HBM latency across serial tiles.
// __launch_bounds__(320,4): cap VGPR at 128 so occupancy (3 blocks/CU)
// matches the measured 4-kernel path -> co-residency safe via occupancy API.
// ============================================================
__global__ __launch_bounds__(320, 4)
void fused_kernel(const float* __restrict__ x,
                  const float* __restrict__ gamma,
                  const float* __restrict__ beta,
                  float* __restrict__ out,
                  float* __restrict__ part1,
                  float* __restrict__ abuf,
                  int ntiles, int nblocks) {
    __shared__ __align__(16) float win[R_ * WSTRIDE];     // 10496 B
    __shared__ __align__(16) float cv2[120 * CV_S];       //  9600 B
    __shared__ __align__(16) float featB[80 * FB_S];      //  6400 B
    __shared__ double rsd[256], rsd2[256];                //  4096 B

    const int t = threadIdx.x;      // 0..319 == output channel
    const int c = t;
    int pi = 0, pj = 0, pp = 0;
    if (c < 240) {
        pp = (c < 120) ? c : (c - 120);
        int b = PIJ[pp];
        pi = b >> 4; pj = b & 15;
    }
    const int c2 = c - 240;
    const int base = blockIdx.x * ntiles;

    float acc = 0.f, acc2 = 0.f;     // own channel
    float accB = 0.f, accB2 = 0.f;   // c<120: cov channel c+120 (stats pass)
    float scale = 0.f, shift = 0.f;

    float4 pf0, pf1;
    auto load_pf = [&](int tile) {
        const float4* s = reinterpret_cast<const float4*>(x) + (size_t)tile * 640;
        pf0 = s[t]; pf1 = s[t + 320];
    };

    auto run_pass = [&](bool apply) {
        if (base < NTILES_TOTAL) load_pf(base);
#pragma unroll 1
        for (int tt = 0; tt < ntiles; ++tt) {
            const int tile = base + tt;
            const bool valid = tile < NTILES_TOTAL;
            __syncthreads();   // previous iteration readers done
            if (valid) {
                // stage prefetched 16 rows x 160 floats
                const int q0 = t, q1 = t + 320;
                reinterpret_cast<float4*>(win)[(q0 / 40) * (WSTRIDE / 4) + (q0 % 40)] = pf0;
                reinterpret_cast<float4*>(win)[(q1 / 40) * (WSTRIDE / 4) + (q1 % 40)] = pf1;
            }
            if (tt + 1 < ntiles && tile + 1 < NTILES_TOTAL) load_pf(tile + 1);
            __syncthreads();

            // ---- phase 2: Gram (t<160) || scalar families (t>=256) ----
            if (valid) {
                if (t < 160) {
                    const int r = t & 15, q = t >> 4;   // q = 0..9
                    const float* wr = win + r * WSTRIDE;
                    if (q < 6) {
                        const int i0 = (q < 3) ? 0 : ((q < 5) ? 4 : 8);
                        const int j0 = (q == 0) ? 4 : ((q == 1 || q == 3) ? 8 : 12);
                        float gacc[4][4];
#pragma unroll
                        for (int a = 0; a < 4; ++a)
#pragma unroll
                            for (int b = 0; b < 4; ++b) gacc[a][b] = 0.f;
#pragma unroll
                        for (int d = 0; d < 10; ++d) {
                            float4 vi = *reinterpret_cast<const float4*>(wr + d * 16 + i0);
                            float4 vj = *reinterpret_cast<const float4*>(wr + d * 16 + j0);
                            float ai[4] = {vi.x, vi.y, vi.z, vi.w};
                            float aj[4] = {vj.x, vj.y, vj.z, vj.w};
#pragma unroll
                            for (int a = 0; a < 4; ++a)
#pragma unroll
                                for (int b = 0; b < 4; ++b)
                                    gacc[a][b] += ai[a] * aj[b];
                        }
#pragma unroll
                        for (int a = 0; a < 4; ++a) {
                            int i = i0 + a;
                            int bs = i * 15 - (i * (i - 1)) / 2 - i - 1;
#pragma unroll
                            for (int b = 0; b < 4; ++b)
                                cv2[(bs + j0 + b) * CV_S + r] = gacc[a][b] * 0.1f;
                        }
                    } else {
                        const int i0 = (q - 6) << 2;
                        float g01 = 0.f, g02 = 0.f, g03 = 0.f,
                              g12 = 0.f, g13 = 0.f, g23 = 0.f;
#pragma unroll
                        for (int d = 0; d < 10; ++d) {
                            float4 vi = *reinterpret_cast<const float4*>(wr + d * 16 + i0);
                            float a0 = vi.x, a1 = vi.y, a2 = vi.z, a3 = vi.w;
                            g01 += a0 * a1; g02 += a0 * a2; g03 += a0 * a3;
                            g12 += a1 * a2; g13 += a1 * a3; g23 += a2 * a3;
                        }
                        cv2[pair_idx(i0 + 0, i0 + 1) * CV_S + r] = g01 * 0.1f;
                        cv2[pair_idx(i0 + 0, i0 + 2) * CV_S + r] = g02 * 0.1f;
                        cv2[pair_idx(i0 + 0, i0 + 3) * CV_S + r] = g03 * 0.1f;
                        cv2[pair_idx(i0 + 1, i0 + 2) * CV_S + r] = g12 * 0.1f;
                        cv2[pair_idx(i0 + 1, i0 + 3) * CV_S + r] = g13 * 0.1f;
                        cv2[pair_idx(i0 + 2, i0 + 3) * CV_S + r] = g23 * 0.1f;
                    }
                } else if (t >= 256) {
                    const int lane = t - 256;                 // 0..63
                    const int r = lane & 15;
                    const int c0 = (lane >> 4) << 2;          // 0,4,8,12
                    const float* wr = win + r * WSTRIDE + c0;
                    float sm[4], sq[4], dec[4], first[4], last[4];
#pragma unroll
                    for (int k = 0; k < 4; ++k) { sm[k] = 0.f; sq[k] = 0.f; dec[k] = 0.f; }
#pragma unroll
                    for (int d = 0; d < 10; ++d) {
                        float4 v = *reinterpret_cast<const float4*>(wr + d * 16);
                        float a[4] = {v.x, v.y, v.z, v.w};
#pragma unroll
                        for (int k = 0; k < 4; ++k) {
                            sm[k] += a[k];
                            sq[k] += a[k] * a[k];
                            dec[k] += a[k] * (float)(d + 1);
                            if (d == 0) first[k] = a[k];
                            if (d == 9) last[k]  = a[k];
                        }
                    }
#pragma unroll
                    for (int k = 0; k < 4; ++k) {
                        int ch = c0 + k;
                        float m = sm[k] * 0.1f;
                        float var = fmaxf(sq[k] * 0.1f - m * m, 0.f);
                        float s = sqrtf(var);
                        featB[(0 * 16 + ch) * FB_S + r] = s;
                        featB[(1 * 16 + ch) * FB_S + r] = m / (s + EPS_F);
                        featB[(2 * 16 + ch) * FB_S + r] = last[k] / first[k] - 1.f;
                        featB[(3 * 16 + ch) * FB_S + r] = dec[k] * (1.f / 55.f);
                        featB[(4 * 16 + ch) * FB_S + r] = m;
                    }
                }
            }
            __syncthreads();

            // ---- phase 3: outputs / accumulation (channel-per-thread) ----
            if (valid) {
                if (!apply && c >= 120 && c < 240) {
                    // cov accumulated by the matching corr thread
                } else {
#pragma unroll
                    for (int rb4 = 0; rb4 < 4; ++rb4) {
                        const int rb = rb4 * 4;
                        if (c < 120) {
                            float4 g4  = *reinterpret_cast<const float4*>(cv2 + pp * CV_S + rb);
                            float4 mi4 = *reinterpret_cast<const float4*>(featB + (64 + pi) * FB_S + rb);
                            float4 mj4 = *reinterpret_cast<const float4*>(featB + (64 + pj) * FB_S + rb);
                            float4 si4 = *reinterpret_cast<const float4*>(featB + pi * FB_S + rb);
                            float4 sj4 = *reinterpret_cast<const float4*>(featB + pj * FB_S + rb);
                            float g[4]  = {g4.x, g4.y, g4.z, g4.w};
                            float mi[4] = {mi4.x, mi4.y, mi4.z, mi4.w};
                            float mj[4] = {mj4.x, mj4.y, mj4.z, mj4.w};
                            float si[4] = {si4.x, si4.y, si4.z, si4.w};
                            float sj[4] = {sj4.x, sj4.y, sj4.z, sj4.w};
#pragma unroll
                            for (int k = 0; k < 4; ++k) {
                                float num = g[k] - mi[k] * mj[k];
                                float cr  = num / (si[k] * sj[k] + EPS_F);
                                if (apply) {
                                    out[(size_t)tile * (R_ * OUTC) + (rb + k) * OUTC + c]
                                        = cr * scale + shift;
                                } else {
                                    acc += cr;  acc2 += cr * cr;
                                    accB += num; accB2 += num * num;
                                }
                            }
                        } else if (c < 240) {
                            // reached only when apply==true
                            float4 g4  = *reinterpret_cast<const float4*>(cv2 + pp * CV_S + rb);
                            float4 mi4 = *reinterpret_cast<const float4*>(featB + (64 + pi) * FB_S + rb);
                            float4 mj4 = *reinterpret_cast<const float4*>(featB + (64 + pj) * FB_S + rb);
                            float g[4]  = {g4.x, g4.y, g4.z, g4.w};
                            float mi[4] = {mi4.x, mi4.y, mi4.z, mi4.w};
                            float mj[4] = {mj4.x, mj4.y, mj4.z, mj4.w};
#pragma unroll
                            for (int k = 0; k < 4; ++k) {
                                float num = g[k] - mi[k] * mj[k];
                                out[(size_t)tile * (R_ * OUTC) + (rb + k) * OUTC + c]
                                    = num * scale + shift;
                            }
                        } else {
                            float4 f4 = *reinterpret_cast<const float4*>(featB + c2 * FB_S + rb);
                            float vals[4] = {f4.x, f4.y, f4.z, f4.w};
#pragma unroll
                            for (int k = 0; k < 4; ++k) {
                                if (apply) {
                                    out[(size_t)tile * (R_ * OUTC) + (rb + k) * OUTC + c]
                                        = vals[k] * scale + shift;
                                } else {
                                    acc += vals[k]; acc2 += vals[k] * vals[k];
                                }
                            }
                        }
                    }
                }
            }
        }
    };

    // ---- pass A: stats ----
    run_pass(false);
    {
        float* db = part1 + (size_t)blockIdx.x * 640;
        if (c < 120) {
            db[c]       = acc;   db[c + 320] = acc2;
            db[c + 120] = accB;  db[c + 440] = accB2;
        } else if (c >= 240) {
            db[c]       = acc;   db[c + 320] = acc2;
        }
    }
    __threadfence();
    cg::this_grid().sync();

    // ---- pass B: finalize (blocks 0..319, one channel each) ----
    if (blockIdx.x < OUTC) {
        const int ch = blockIdx.x;
        if (t < 256) {
            double s = 0.0, s2 = 0.0;
            for (int r = t; r < nblocks; r += 256) {
                s  += (double)part1[(size_t)r * 640 + ch];
                s2 += (double)part1[(size_t)r * 640 + ch + OUTC];
            }
            rsd[t] = s; rsd2[t] = s2;
        }
        __syncthreads();
        for (int off = 128; off; off >>= 1) {
            if (t < off) { rsd[t] += rsd[t + off]; rsd2[t] += rsd2[t + off]; }
            __syncthreads();
        }
        if (t == 0) {
            const double invN = 1.0 / (double)NROWS;
            double m = rsd[0] * invN;
            double v = rsd2[0] * invN - m * m;
            if (v < 0.0) v = 0.0;
            float a = gamma[ch] / sqrtf((float)v + EPS_BN);
            abuf[ch] = a;
            abuf[ch + OUTC] = beta[ch] - (float)m * a;
        }
    }
    __threadfence();
    cg::this_grid().sync();

    // ---- pass C: apply ----
    scale = abuf[c];
    shift = abuf[c + OUTC];
    run_pass(true);
}

// ============================================================
// Fallback path (round-10 proven 4-kernel pipeline)
// ============================================================
template<int MODE, int NTILES>
__global__ __launch_bounds__(320)
void fe_kernel(const float* __restrict__ x, float* __restrict__ dst,
               const float* __restrict__ ab) {
    __shared__ __align__(16) float win[R_ * WSTRIDE];
    __shared__ __align__(16) float cv2[120 * CV_S];
    __shared__ __align__(16) float featB[80 * FB_S];

    const int t = threadIdx.x;
    const int c = t;
    int pi = 0, pj = 0, pp = 0;
    if (c < 240) {
        pp = (c < 120) ? c : (c - 120);
        int b = PIJ[pp];
        pi = b >> 4; pj = b & 15;
    }
    const int c2 = c - 240;

    float scale = 0.f, shift = 0.f;
    if (MODE == 1) { scale = ab[c]; shift = ab[c + OUTC]; }

    float acc = 0.f, acc2 = 0.f;
    float accB = 0.f, accB2 = 0.f;

#pragma unroll 1
    for (int tt = 0; tt < NTILES; ++tt) {
        const int tile = blockIdx.x * NTILES + tt;
        const float4* src = reinterpret_cast<const float4*>(x) + (size_t)tile * 640;

        __syncthreads();
#pragma unroll
        for (int k = 0; k < 2; ++k) {
            int q = t + k * 320;
            float4 v = src[q];
            int row = q / 40, pos = q % 40;
            reinterpret_cast<float4*>(win)[row * (WSTRIDE / 4) + pos] = v;
        }
        __syncthreads();

        if (t < 160) {
            const int r = t & 15, q = t >> 4;
            const float* wr = win + r * WSTRIDE;
            if (q < 6) {
                const int i0 = (q < 3) ? 0 : ((q < 5) ? 4 : 8);
                const int j0 = (q == 0) ? 4 : ((q == 1 || q == 3) ? 8 : 12);
                float gacc[4][4];
#pragma unroll
                for (int a = 0; a < 4; ++a)
#pragma unroll
                    for (int b = 0; b < 4; ++b) gacc[a][b] = 0.f;
#pragma unroll
                for (int d = 0; d < 10; ++d) {
                    float4 vi = *reinterpret_cast<const float4*>(wr + d * 16 + i0);
                    float4 vj = *reinterpret_cast<const float4*>(wr + d * 16 + j0);
                    float ai[4] = {vi.x, vi.y, vi.z, vi.w};
                    float aj[4] = {vj.x, vj.y, vj.z, vj.w};
#pragma unroll
                    for (int a = 0; a < 4; ++a)
#pragma unroll
                        for (int b = 0; b < 4; ++b)
                            gacc[a][b] += ai[a] * aj[b];
                }
#pragma unroll
                for (int a = 0; a < 4; ++a) {
                    int i = i0 + a;
                    int bs = i * 15 - (i * (i - 1)) / 2 - i - 1;
#pragma unroll
                    for (int b = 0; b < 4; ++b)
                        cv2[(bs + j0 + b) * CV_S + r] = gacc[a][b] * 0.1f;
                }
            } else {
                const int i0 = (q - 6) << 2;
                float g01 = 0.f, g02 = 0.f, g03 = 0.f,
                      g12 = 0.f, g13 = 0.f, g23 = 0.f;
#pragma unroll
                for (int d = 0; d < 10; ++d) {
                    float4 vi = *reinterpret_cast<const float4*>(wr + d * 16 + i0);
                    float a0 = vi.x, a1 = vi.y, a2 = vi.z, a3 = vi.w;
                    g01 += a0 * a1; g02 += a0 * a2; g03 += a0 * a3;
                    g12 += a1 * a2; g13 += a1 * a3; g23 += a2 * a3;
                }
                cv2[pair_idx(i0 + 0, i0 + 1) * CV_S + r] = g01 * 0.1f;
                cv2[pair_idx(i0 + 0, i0 + 2) * CV_S + r] = g02 * 0.1f;
                cv2[pair_idx(i0 + 0, i0 + 3) * CV_S + r] = g03 * 0.1f;
                cv2[pair_idx(i0 + 1, i0 + 2) * CV_S + r] = g12 * 0.1f;
                cv2[pair_idx(i0 + 1, i0 + 3) * CV_S + r] = g13 * 0.1f;
                cv2[pair_idx(i0 + 2, i0 + 3) * CV_S + r] = g23 * 0.1f;
            }
        } else if (t >= 256) {
            const int lane = t - 256;
            const int r = lane & 15;
            const int c0 = (lane >> 4) << 2;
            const float* wr = win + r * WSTRIDE + c0;
            float sm[4], sq[4], dec[4], first[4], last[4];
#pragma unroll
            for (int k = 0; k < 4; ++k) { sm[k] = 0.f; sq[k] = 0.f; dec[k] = 0.f; }
#pragma unroll
            for (int d = 0; d < 10; ++d) {
                float4 v = *reinterpret_cast<const float4*>(wr + d * 16);
                float a[4] = {v.x, v.y, v.z, v.w};
#pragma unroll
                for (int k = 0; k < 4; ++k) {
                    sm[k] += a[k];
                    sq[k] += a[k] * a[k];
                    dec[k] += a[k] * (float)(d + 1);
                    if (d == 0) first[k] = a[k];
                    if (d == 9) last[k]  = a[k];
                }
            }
#pragma unroll
            for (int k = 0; k < 4; ++k) {
                int ch = c0 + k;
                float m = sm[k] * 0.1f;
                float var = fmaxf(sq[k] * 0.1f - m * m, 0.f);
                float s = sqrtf(var);
                featB[(0 * 16 + ch) * FB_S + r] = s;
                featB[(1 * 16 + ch) * FB_S + r] = m / (s + EPS_F);
                featB[(2 * 16 + ch) * FB_S + r] = last[k] / first[k] - 1.f;
                featB[(3 * 16 + ch) * FB_S + r] = dec[k] * (1.f / 55.f);
                featB[(4 * 16 + ch) * FB_S + r] = m;
            }
        }
        __syncthreads();

        if (MODE == 0 && c >= 120 && c < 240) {
        } else {
#pragma unroll
            for (int rb4 = 0; rb4 < 4; ++rb4) {
                const int rb = rb4 * 4;
                if (c < 120) {
                    float4 g4  = *reinterpret_cast<const float4*>(cv2 + pp * CV_S + rb);
                    float4 mi4 = *reinterpret_cast<const float4*>(featB + (64 + pi) * FB_S + rb);
                    float4 mj4 = *reinterpret_cast<const float4*>(featB + (64 + pj) * FB_S + rb);
                    float4 si4 = *reinterpret_cast<const float4*>(featB + pi * FB_S + rb);
                    float4 sj4 = *reinterpret_cast<const float4*>(featB + pj * FB_S + rb);
                    float g[4]  = {g4.x, g4.y, g4.z, g4.w};
                    float mi[4] = {mi4.x, mi4.y, mi4.z, mi4.w};
                    float mj[4] = {mj4.x, mj4.y, mj4.z, mj4.w};
                    float si[4] = {si4.x, si4.y, si4.z, si4.w};
                    float sj[4] = {sj4.x, sj4.y, sj4.z, sj4.w};
#pragma unroll
                    for (int k = 0; k < 4; ++k) {
                        float num = g[k] - mi[k] * mj[k];
                        float cr  = num / (si[k] * sj[k] + EPS_F);
                        if (MODE == 1) {
                            dst[(size_t)tile * (R_ * OUTC) + (rb + k) * OUTC + c]
                                = cr * scale + shift;
                        } else {
                            acc += cr;  acc2 += cr * cr;
                            accB += num; accB2 += num * num;
                        }
                    }
                } else if (c < 240) {
                    float4 g4  = *reinterpret_cast<const float4*>(cv2 + pp * CV_S + rb);
                    float4 mi4 = *reinterpret_cast<const float4*>(featB + (64 + pi) * FB_S + rb);
                    float4 mj4 = *reinterpret_cast<const float4*>(featB + (64 + pj) * FB_S + rb);
                    float g[4]  = {g4.x, g4.y, g4.z, g4.w};
                    float mi[4] = {mi4.x, mi4.y, mi4.z, mi4.w};
                    float mj[4] = {mj4.x, mj4.y, mj4.z, mj4.w};
#pragma unroll
                    for (int k = 0; k < 4; ++k) {
                        float num = g[k] - mi[k] * mj[k];
                        dst[(size_t)tile * (R_ * OUTC) + (rb + k) * OUTC + c]
                            = num * scale + shift;
                    }
                } else {
                    float4 f4 = *reinterpret_cast<const float4*>(featB + c2 * FB_S + rb);
                    float vals[4] = {f4.x, f4.y, f4.z, f4.w};
#pragma unroll
                    for (int k = 0; k < 4; ++k) {
                        if (MODE == 1) {
                            dst[(size_t)tile * (R_ * OUTC) + (rb + k) * OUTC + c]
                                = vals[k] * scale + shift;
                        } else {
                            acc += vals[k]; acc2 += vals[k] * vals[k];
                        }
                    }
                }
            }
        }
    }

    if (MODE == 0) {
        float* db = dst + (size_t)blockIdx.x * 640;
        if (c < 120) {
            db[c]       = acc;   db[c + 320] = acc2;
            db[c + 120] = accB;  db[c + 440] = accB2;
        } else if (c >= 240) {
            db[c]       = acc;   db[c + 320] = acc2;
        }
    }
}

__global__ __launch_bounds__(256)
void reduceA_kernel(const float* __restrict__ part1, float* __restrict__ part2,
                    int nb) {
    const int rows = nb / RA_BLOCKS;
    const int b = blockIdx.x;
    for (int v = threadIdx.x; v < 640; v += 256) {
        float s = 0.f;
        for (int j = 0; j < rows; ++j)
            s += part1[(size_t)(b + RA_BLOCKS * j) * 640 + v];
        part2[(size_t)b * 640 + v] = s;
    }
}

__global__ __launch_bounds__(256)
void finalize_kernel(const float* __restrict__ part2,
                     const float* __restrict__ gamma,
                     const float* __restrict__ beta,
                     float* __restrict__ ab) {
    __shared__ double rs[256], rs2[256];
    const int c = blockIdx.x, t = threadIdx.x;
    double s = 0.0, s2 = 0.0;
    for (int r = t; r < RA_BLOCKS; r += 256) {
        s  += (double)part2[(size_t)r * 640 + c];
        s2 += (double)part2[(size_t)r * 640 + c + OUTC];
    }
    rs[t] = s; rs2[t] = s2;
    __syncthreads();
    for (int off = 128; off; off >>= 1) {
        if (t < off) { rs[t] += rs[t + off]; rs2[t] += rs2[t + off]; }
        __syncthreads();
    }
    if (t == 0) {
        const double invN = 1.0 / (double)NROWS;
        double m = rs[0] * invN;
        double v = rs2[0] * invN - m * m;
        if (v < 0.0) v = 0.0;
        float a = gamma[c] / sqrtf((float)v + EPS_BN);
        ab[c] = a;
        ab[OUTC + c] = beta[c] - (float)m * a;
    }
}

extern "C" void kernel_launch(void* const* d_in, const int* in_sizes, int n_in,
                              void* d_out, int out_size, void* d_ws, size_t ws_size,
                              hipStream_t stream) {
    const float* x     = (const float*)d_in[0];
    const float* gamma = (const float*)d_in[1];
    const float* beta  = (const float*)d_in[2];
    float* out = (float*)d_out;

    // ---- try cooperative fused path (all queries deterministic per build) ----
    int dev = 0;
    (void)hipGetDevice(&dev);
    int coop = 0;
    (void)hipDeviceGetAttribute(&coop, hipDeviceAttributeCooperativeLaunch, dev);
    int nsm = 0;
    (void)hipDeviceGetAttribute(&nsm, hipDeviceAttributeMultiprocessorCount, dev);
    int blocks_per_cu = 0;
    (void)hipOccupancyMaxActiveBlocksPerMultiprocessor(
        &blocks_per_cu, (const void*)fused_kernel, 320, 0);

    long grid_l = (long)blocks_per_cu * (long)nsm;
    if (grid_l > NTILES_TOTAL) grid_l = NTILES_TOTAL;
    const int grid = (int)grid_l;
    const size_t coop_ws_need = ((size_t)grid * 640 + 640) * sizeof(float);

    if (coop && grid >= OUTC && coop_ws_need <= ws_size) {
        int ntiles = (NTILES_TOTAL + grid - 1) / grid;
        float* part1 = (float*)d_ws;                 // grid*640 floats
        float* abuf  = part1 + (size_t)grid * 640;   // 640 floats
        int nblocks = grid;
        void* args[] = {(void*)&x, (void*)&gamma, (void*)&beta, (void*)&out,
                        (void*)&part1, (void*)&abuf, (void*)&ntiles, (void*)&nblocks};
        hipError_t err = hipLaunchCooperativeKernel(
            (const void*)fused_kernel, dim3(grid), dim3(320), args, 0, stream);
        if (err == hipSuccess) return;
        // fall through to the 4-kernel path on failure
    }

    // ---- fallback: round-10 proven 4-kernel pipeline ----
    const size_t need1 = (size_t)NTILES_TOTAL * 640 * 4
                       + (size_t)RA_BLOCKS * 640 * 4 + 640 * 4;
    const int nb = (need1 <= ws_size) ? NTILES_TOTAL : (NTILES_TOTAL / 8);

    float* part1 = (float*)d_ws;
    float* part2 = part1 + (size_t)nb * 640;
    float* ab    = part2 + (size_t)RA_BLOCKS * 640;

    if (nb == NTILES_TOTAL)
        fe_kernel<0, 1><<<nb, 320, 0, stream>>>(x, part1, nullptr);
    else
        fe_kernel<0, 8><<<nb, 320, 0, stream>>>(x, part1, nullptr);
    reduceA_kernel<<<RA_BLOCKS, 256, 0, stream>>>(part1, part2, nb);
    finalize_kernel<<<OUTC, 256, 0, stream>>>(part2, gamma, beta, ab);
    fe_kernel<1, 1><<<NTILES_TOTAL, 320, 0, stream>>>(x, out, ab);
}

// Round 13
// 131.238 us; speedup vs baseline: 2.9053x; 2.9053x over previous
//
#include <hip/hip_runtime.h>

// B=8192, T=240, C=16, DAYS=STRIDE=10 -> W=24 windows tiling T exactly.
// Row r reads contiguous x[r*160 .. r*160+159]. 320 output channels:
// [corr(120), cov(120), std(16), zscore(16), ret(16), decay(16), mean(16)].
#define NROWS   196608
#define NTILES_TOTAL 12288    // 196608 rows / 16 rows-per-tile
#define OUTC    320
#define R_      16            // rows per LDS tile
#define WSTRIDE 164           // win LDS row stride (floats), float4-aligned
#define CV_S    20            // cv2 [pair][row] stride (floats), 16B-aligned
#define FB_S    20            // featB [chan][row] stride (floats), 16B-aligned
#define EPS_F   1e-8f
#define EPS_BN  1e-5f
#define RA_BLOCKS 768         // stage-A reduce grid

// p(i,j) for i<j, row-major triu: p = i*15 - i(i-1)/2 + j - i - 1
__device__ __forceinline__ int pair_idx(int i, int j) {
    return i * 15 - (i * (i - 1)) / 2 + j - i - 1;
}

// pair p -> packed (i<<4)|j for triu_indices(16, k=1), row-major
__device__ const unsigned char PIJ[120] = {
    0x01,0x02,0x03,0x04,0x05,0x06,0x07,0x08,0x09,0x0A,0x0B,0x0C,0x0D,0x0E,0x0F,
    0x12,0x13,0x14,0x15,0x16,0x17,0x18,0x19,0x1A,0x1B,0x1C,0x1D,0x1E,0x1F,
    0x23,0x24,0x25,0x26,0x27,0x28,0x29,0x2A,0x2B,0x2C,0x2D,0x2E,0x2F,
    0x34,0x35,0x36,0x37,0x38,0x39,0x3A,0x3B,0x3C,0x3D,0x3E,0x3F,
    0x45,0x46,0x47,0x48,0x49,0x4A,0x4B,0x4C,0x4D,0x4E,0x4F,
    0x56,0x57,0x58,0x59,0x5A,0x5B,0x5C,0x5D,0x5E,0x5F,
    0x67,0x68,0x69,0x6A,0x6B,0x6C,0x6D,0x6E,0x6F,
    0x78,0x79,0x7A,0x7B,0x7C,0x7D,0x7E,0x7F,
    0x89,0x8A,0x8B,0x8C,0x8D,0x8E,0x8F,
    0x9A,0x9B,0x9C,0x9D,0x9E,0x9F,
    0xAB,0xAC,0xAD,0xAE,0xAF,
    0xBC,0xBD,0xBE,0xBF,
    0xCD,0xCE,0xCF,
    0xDE,0xDF,
    0xEF
};

// 320 threads/block (5 waves). Thread t owns OUTPUT CHANNEL t.
// Phase 2 (round-7 proven layout — wave-uniform roles; finer intra-wave
// role mixing regressed in round 8; launch_bounds min-waves caused a
// 40-VGPR spill catastrophe in round 12 — keep plain (320)):
//   t in [0,160): Gram register blocks (q = t>>4: q<6 off-diag 4x4,
//                 q>=6 diag 4x4), r = t&15
//   t in [256,320): per-(row, chan-quad) mean/std/z/ret/decay -> featB
// MODE=0: dst = part1[block][640] (sum[320] | sumsq[320]).
// MODE=1: dst = output; ab = {scale[320], shift[320]} in registers.
template<int MODE, int NTILES>
__global__ __launch_bounds__(320)
void fe_kernel(const float* __restrict__ x, float* __restrict__ dst,
               const float* __restrict__ ab) {
    __shared__ __align__(16) float win[R_ * WSTRIDE];     // 10496 B
    __shared__ __align__(16) float cv2[120 * CV_S];       //  9600 B  g=E[xi*xj], [p][r]
    __shared__ __align__(16) float featB[80 * FB_S];      //  6400 B  [c-240][r]

    const int t = threadIdx.x;      // 0..319 == output channel

    // ---- per-thread channel invariants ----
    const int c = t;
    int pi = 0, pj = 0, pp = 0;
    if (c < 240) {
        pp = (c < 120) ? c : (c - 120);
        int b = PIJ[pp];
        pi = b >> 4; pj = b & 15;
    }
    const int c2 = c - 240;

    float scale = 0.f, shift = 0.f;
    if (MODE == 1) { scale = ab[c]; shift = ab[c + OUTC]; }

    float acc = 0.f, acc2 = 0.f;

#pragma unroll 1
    for (int tt = 0; tt < NTILES; ++tt) {
        const int tile = blockIdx.x * NTILES + tt;
        const float4* src = reinterpret_cast<const float4*>(x) + (size_t)tile * 640;

        __syncthreads();   // previous iteration readers done
        // ---- stage 16 rows x 160 floats: 640 float4, 2 per thread ----
#pragma unroll
        for (int k = 0; k < 2; ++k) {
            int q = t + k * 320;
            float4 v = src[q];
            int row = q / 40, pos = q % 40;
            reinterpret_cast<float4*>(win)[row * (WSTRIDE / 4) + pos] = v;
        }
        __syncthreads();

        // ---- phase 2: Gram (t<160) || scalar families (t>=256) ----
        if (t < 160) {
            const int r = t & 15, q = t >> 4;   // q = 0..9
            const float* wr = win + r * WSTRIDE;
            if (q < 6) {
                // off-diagonal 4x4 block
                const int i0 = (q < 3) ? 0 : ((q < 5) ? 4 : 8);
                const int j0 = (q == 0) ? 4 : ((q == 1 || q == 3) ? 8 : 12);
                float gacc[4][4];
#pragma unroll
                for (int a = 0; a < 4; ++a)
#pragma unroll
                    for (int b = 0; b < 4; ++b) gacc[a][b] = 0.f;
#pragma unroll
                for (int d = 0; d < 10; ++d) {
                    float4 vi = *reinterpret_cast<const float4*>(wr + d * 16 + i0);
                    float4 vj = *reinterpret_cast<const float4*>(wr + d * 16 + j0);
                    float ai[4] = {vi.x, vi.y, vi.z, vi.w};
                    float aj[4] = {vj.x, vj.y, vj.z, vj.w};
#pragma unroll
                    for (int a = 0; a < 4; ++a)
#pragma unroll
                        for (int b = 0; b < 4; ++b)
                            gacc[a][b] += ai[a] * aj[b];
                }
#pragma unroll
                for (int a = 0; a < 4; ++a) {
                    int i = i0 + a;
                    int base = i * 15 - (i * (i - 1)) / 2 - i - 1;
#pragma unroll
                    for (int b = 0; b < 4; ++b)
                        cv2[(base + j0 + b) * CV_S + r] = gacc[a][b] * 0.1f;
                }
            } else {
                // diagonal 4x4 block: 6 upper pairs
                const int i0 = (q - 6) << 2;
                float g01 = 0.f, g02 = 0.f, g03 = 0.f,
                      g12 = 0.f, g13 = 0.f, g23 = 0.f;
#pragma unroll
                for (int d = 0; d < 10; ++d) {
                    float4 vi = *reinterpret_cast<const float4*>(wr + d * 16 + i0);
                    float a0 = vi.x, a1 = vi.y, a2 = vi.z, a3 = vi.w;
                    g01 += a0 * a1; g02 += a0 * a2; g03 += a0 * a3;
                    g12 += a1 * a2; g13 += a1 * a3; g23 += a2 * a3;
                }
                cv2[pair_idx(i0 + 0, i0 + 1) * CV_S + r] = g01 * 0.1f;
                cv2[pair_idx(i0 + 0, i0 + 2) * CV_S + r] = g02 * 0.1f;
                cv2[pair_idx(i0 + 0, i0 + 3) * CV_S + r] = g03 * 0.1f;
                cv2[pair_idx(i0 + 1, i0 + 2) * CV_S + r] = g12 * 0.1f;
                cv2[pair_idx(i0 + 1, i0 + 3) * CV_S + r] = g13 * 0.1f;
                cv2[pair_idx(i0 + 2, i0 + 3) * CV_S + r] = g23 * 0.1f;
            }
        } else if (t >= 256) {
            const int lane = t - 256;                 // 0..63
            const int r = lane & 15;
            const int c0 = (lane >> 4) << 2;          // 0,4,8,12
            const float* wr = win + r * WSTRIDE + c0;
            float sm[4], sq[4], dec[4], first[4], last[4];
#pragma unroll
            for (int k = 0; k < 4; ++k) { sm[k] = 0.f; sq[k] = 0.f; dec[k] = 0.f; }
#pragma unroll
            for (int d = 0; d < 10; ++d) {
                float4 v = *reinterpret_cast<const float4*>(wr + d * 16);
                float a[4] = {v.x, v.y, v.z, v.w};
#pragma unroll
                for (int k = 0; k < 4; ++k) {
                    sm[k] += a[k];
                    sq[k] += a[k] * a[k];
                    dec[k] += a[k] * (float)(d + 1);
                    if (d == 0) first[k] = a[k];
                    if (d == 9) last[k]  = a[k];
                }
            }
#pragma unroll
            for (int k = 0; k < 4; ++k) {
                int ch = c0 + k;
                float m = sm[k] * 0.1f;
                float var = fmaxf(sq[k] * 0.1f - m * m, 0.f);
                float s = sqrtf(var);
                featB[(0 * 16 + ch) * FB_S + r] = s;                       // std
                featB[(1 * 16 + ch) * FB_S + r] = m / (s + EPS_F);         // zscore
                featB[(2 * 16 + ch) * FB_S + r] = last[k] / first[k] - 1.f;// ret
                featB[(3 * 16 + ch) * FB_S + r] = dec[k] * (1.f / 55.f);   // decay
                featB[(4 * 16 + ch) * FB_S + r] = m;                       // mean
            }
        }
        __syncthreads();

        // ---- phase 3: outputs / accumulation (channel-per-thread) ----
#pragma unroll
        for (int rb4 = 0; rb4 < 4; ++rb4) {
            const int rb = rb4 * 4;
            float vals[4];
            if (c < 240) {
                float4 g4  = *reinterpret_cast<const float4*>(cv2 + pp * CV_S + rb);
                float4 mi4 = *reinterpret_cast<const float4*>(featB + (64 + pi) * FB_S + rb);
                float4 mj4 = *reinterpret_cast<const float4*>(featB + (64 + pj) * FB_S + rb);
                float g[4]  = {g4.x, g4.y, g4.z, g4.w};
                float mi[4] = {mi4.x, mi4.y, mi4.z, mi4.w};
                float mj[4] = {mj4.x, mj4.y, mj4.z, mj4.w};
                if (c < 120) {
                    float4 si4 = *reinterpret_cast<const float4*>(featB + pi * FB_S + rb);
                    float4 sj4 = *reinterpret_cast<const float4*>(featB + pj * FB_S + rb);
                    float si[4] = {si4.x, si4.y, si4.z, si4.w};
                    float sj[4] = {sj4.x, sj4.y, sj4.z, sj4.w};
#pragma unroll
                    for (int k = 0; k < 4; ++k)
                        vals[k] = (g[k] - mi[k] * mj[k]) / (si[k] * sj[k] + EPS_F);
                } else {
#pragma unroll
                    for (int k = 0; k < 4; ++k)
                        vals[k] = g[k] - mi[k] * mj[k];
                }
            } else {
                float4 f4 = *reinterpret_cast<const float4*>(featB + c2 * FB_S + rb);
                vals[0] = f4.x; vals[1] = f4.y; vals[2] = f4.z; vals[3] = f4.w;
            }
#pragma unroll
            for (int k = 0; k < 4; ++k) {
                if (MODE == 1) {
                    dst[(size_t)tile * (R_ * OUTC) + (rb + k) * OUTC + c]
                        = vals[k] * scale + shift;
                } else {
                    acc += vals[k];
                    acc2 += vals[k] * vals[k];
                }
            }
        }
    }

    if (MODE == 0) {
        dst[(size_t)blockIdx.x * 640 + t]        = acc;
        dst[(size_t)blockIdx.x * 640 + OUTC + t] = acc2;
    }
}

// Stage-A reduce: 768 blocks; block b sums rows {b + 768*j} of part1[nb][640]
// into part2[b][640]. Row reads coalesced (lanes = consecutive v).
__global__ __launch_bounds__(256)
void reduceA_kernel(const float* __restrict__ part1, float* __restrict__ part2,
                    int nb) {
    const int rows = nb / RA_BLOCKS;            // 8 (or 2 in fallback)
    const int b = blockIdx.x;
    for (int v = threadIdx.x; v < 640; v += 256) {
        float s = 0.f;
        for (int j = 0; j < rows; ++j)
            s += part1[(size_t)(b + RA_BLOCKS * j) * 640 + v];
        part2[(size_t)b * 640 + v] = s;
    }
}

// Final: 320 blocks (one per channel). fp64 column reduce of part2[768][640]
// (1.9 MB -> L2-resident, column reads cheap) with fixed LDS tree.
__global__ __launch_bounds__(256)
void finalize_kernel(const float* __restrict__ part2,
                     const float* __restrict__ gamma,
                     const float* __restrict__ beta,
                     float* __restrict__ ab) {
    __shared__ double rs[256], rs2[256];
    const int c = blockIdx.x, t = threadIdx.x;
    double s = 0.0, s2 = 0.0;
    for (int r = t; r < RA_BLOCKS; r += 256) {
        s  += (double)part2[(size_t)r * 640 + c];
        s2 += (double)part2[(size_t)r * 640 + c + OUTC];
    }
    rs[t] = s; rs2[t] = s2;
    __syncthreads();
    for (int off = 128; off; off >>= 1) {
        if (t < off) { rs[t] += rs[t + off]; rs2[t] += rs2[t + off]; }
        __syncthreads();
    }
    if (t == 0) {
        const double invN = 1.0 / (double)NROWS;
        double m = rs[0] * invN;
        double v = rs2[0] * invN - m * m;
        if (v < 0.0) v = 0.0;
        float a = gamma[c] / sqrtf((float)v + EPS_BN);
        ab[c] = a;
        ab[OUTC + c] = beta[c] - (float)m * a;
    }
}

extern "C" void kernel_launch(void* const* d_in, const int* in_sizes, int n_in,
                              void* d_out, int out_size, void* d_ws, size_t ws_size,
                              hipStream_t stream) {
    const float* x     = (const float*)d_in[0];
    const float* gamma = (const float*)d_in[1];
    const float* beta  = (const float*)d_in[2];
    float* out = (float*)d_out;

    // Stats pass: 2 tiles/block (6144 blocks, 15.7 MB partials). Compile-time
    // fallback to 8 tiles/block if ws is small. ws_size is fixed across
    // calls -> same path every call (deterministic).
    const size_t need2 = (size_t)(NTILES_TOTAL / 2) * 640 * 4
                       + (size_t)RA_BLOCKS * 640 * 4 + 640 * 4;
    const int nb = (need2 <= ws_size) ? (NTILES_TOTAL / 2) : (NTILES_TOTAL / 8);

    float* part1 = (float*)d_ws;                       // nb*640 floats
    float* part2 = part1 + (size_t)nb * 640;           // 768*640 floats
    float* ab    = part2 + (size_t)RA_BLOCKS * 640;    // 640 floats

    if (nb == NTILES_TOTAL / 2)
        fe_kernel<0, 2><<<nb, 320, 0, stream>>>(x, part1, nullptr);
    else
        fe_kernel<0, 8><<<nb, 320, 0, stream>>>(x, part1, nullptr);
    reduceA_kernel<<<RA_BLOCKS, 256, 0, stream>>>(part1, part2, nb);
    finalize_kernel<<<OUTC, 256, 0, stream>>>(part2, gamma, beta, ab);
    fe_kernel<1, 1><<<NTILES_TOTAL, 320, 0, stream>>>(x, out, ab);
}

// Round 14
// 129.055 us; speedup vs baseline: 2.9545x; 1.0169x over previous
//
#include <hip/hip_runtime.h>

// B=8192, T=240, C=16, DAYS=STRIDE=10 -> W=24 windows tiling T exactly.
// Row r reads contiguous x[r*160 .. r*160+159]. 320 output channels:
// [corr(120), cov(120), std(16), zscore(16), ret(16), decay(16), mean(16)].
//
// Best-measured configuration (round 7: 129.1 us). Structure:
//   fe<0,1>: 12288 blocks x 1 tile -> per-block channel partials (31.5 MB)
//   reduceA: 768 blocks, row-coalesced partial reduce (16:1)
//   finalize: 320 blocks, fp64 column reduce of L2-resident 1.9 MB
//   fe<1,1>: 12288 blocks, recompute + fused BN affine, coalesced writes
// Measured component floors: fe<1> ~62us (97% of 6.3 TB/s on 378 MB),
// fe<0> ~46us (LDS-pipe structural, ~2000 cyc/tile), reduction ~12us.
// Known-bad variants (measured): intra-wave role mixing (r8), fused
// column-read finalize (r9), MODE=0 cov-skip (r10), cooperative 3-pass
// fusion w/ launch_bounds min-waves -> 40-VGPR spill (r12), NTILES=2 (r13).
#define NROWS   196608
#define NTILES_TOTAL 12288    // 196608 rows / 16 rows-per-tile
#define OUTC    320
#define R_      16            // rows per LDS tile
#define WSTRIDE 164           // win LDS row stride (floats), float4-aligned
#define CV_S    20            // cv2 [pair][row] stride (floats), 16B-aligned
#define FB_S    20            // featB [chan][row] stride (floats), 16B-aligned
#define EPS_F   1e-8f
#define EPS_BN  1e-5f
#define RA_BLOCKS 768         // stage-A reduce grid

// p(i,j) for i<j, row-major triu: p = i*15 - i(i-1)/2 + j - i - 1
__device__ __forceinline__ int pair_idx(int i, int j) {
    return i * 15 - (i * (i - 1)) / 2 + j - i - 1;
}

// pair p -> packed (i<<4)|j for triu_indices(16, k=1), row-major
__device__ const unsigned char PIJ[120] = {
    0x01,0x02,0x03,0x04,0x05,0x06,0x07,0x08,0x09,0x0A,0x0B,0x0C,0x0D,0x0E,0x0F,
    0x12,0x13,0x14,0x15,0x16,0x17,0x18,0x19,0x1A,0x1B,0x1C,0x1D,0x1E,0x1F,
    0x23,0x24,0x25,0x26,0x27,0x28,0x29,0x2A,0x2B,0x2C,0x2D,0x2E,0x2F,
    0x34,0x35,0x36,0x37,0x38,0x39,0x3A,0x3B,0x3C,0x3D,0x3E,0x3F,
    0x45,0x46,0x47,0x48,0x49,0x4A,0x4B,0x4C,0x4D,0x4E,0x4F,
    0x56,0x57,0x58,0x59,0x5A,0x5B,0x5C,0x5D,0x5E,0x5F,
    0x67,0x68,0x69,0x6A,0x6B,0x6C,0x6D,0x6E,0x6F,
    0x78,0x79,0x7A,0x7B,0x7C,0x7D,0x7E,0x7F,
    0x89,0x8A,0x8B,0x8C,0x8D,0x8E,0x8F,
    0x9A,0x9B,0x9C,0x9D,0x9E,0x9F,
    0xAB,0xAC,0xAD,0xAE,0xAF,
    0xBC,0xBD,0xBE,0xBF,
    0xCD,0xCE,0xCF,
    0xDE,0xDF,
    0xEF
};

// 320 threads/block (5 waves). Thread t owns OUTPUT CHANNEL t.
// Phase 2 (wave-uniform roles): t in [0,160) Gram register blocks
// (q = t>>4: q<6 off-diag 4x4, q>=6 diag 4x4), r = t&15;
// t in [256,320): per-(row, chan-quad) mean/std/z/ret/decay -> featB.
// MODE=0: dst = part1[block][640] (sum[320] | sumsq[320]).
// MODE=1: dst = output; ab = {scale[320], shift[320]} in registers.
template<int MODE, int NTILES>
__global__ __launch_bounds__(320)
void fe_kernel(const float* __restrict__ x, float* __restrict__ dst,
               const float* __restrict__ ab) {
    __shared__ __align__(16) float win[R_ * WSTRIDE];     // 10496 B
    __shared__ __align__(16) float cv2[120 * CV_S];       //  9600 B  g=E[xi*xj], [p][r]
    __shared__ __align__(16) float featB[80 * FB_S];      //  6400 B  [c-240][r]

    const int t = threadIdx.x;      // 0..319 == output channel

    // ---- per-thread channel invariants ----
    const int c = t;
    int pi = 0, pj = 0, pp = 0;
    if (c < 240) {
        pp = (c < 120) ? c : (c - 120);
        int b = PIJ[pp];
        pi = b >> 4; pj = b & 15;
    }
    const int c2 = c - 240;

    float scale = 0.f, shift = 0.f;
    if (MODE == 1) { scale = ab[c]; shift = ab[c + OUTC]; }

    float acc = 0.f, acc2 = 0.f;

#pragma unroll 1
    for (int tt = 0; tt < NTILES; ++tt) {
        const int tile = blockIdx.x * NTILES + tt;
        const float4* src = reinterpret_cast<const float4*>(x) + (size_t)tile * 640;

        __syncthreads();   // previous iteration readers done
        // ---- stage 16 rows x 160 floats: 640 float4, 2 per thread ----
#pragma unroll
        for (int k = 0; k < 2; ++k) {
            int q = t + k * 320;
            float4 v = src[q];
            int row = q / 40, pos = q % 40;
            reinterpret_cast<float4*>(win)[row * (WSTRIDE / 4) + pos] = v;
        }
        __syncthreads();

        // ---- phase 2: Gram (t<160) || scalar families (t>=256) ----
        if (t < 160) {
            const int r = t & 15, q = t >> 4;   // q = 0..9
            const float* wr = win + r * WSTRIDE;
            if (q < 6) {
                // off-diagonal 4x4 block
                const int i0 = (q < 3) ? 0 : ((q < 5) ? 4 : 8);
                const int j0 = (q == 0) ? 4 : ((q == 1 || q == 3) ? 8 : 12);
                float gacc[4][4];
#pragma unroll
                for (int a = 0; a < 4; ++a)
#pragma unroll
                    for (int b = 0; b < 4; ++b) gacc[a][b] = 0.f;
#pragma unroll
                for (int d = 0; d < 10; ++d) {
                    float4 vi = *reinterpret_cast<const float4*>(wr + d * 16 + i0);
                    float4 vj = *reinterpret_cast<const float4*>(wr + d * 16 + j0);
                    float ai[4] = {vi.x, vi.y, vi.z, vi.w};
                    float aj[4] = {vj.x, vj.y, vj.z, vj.w};
#pragma unroll
                    for (int a = 0; a < 4; ++a)
#pragma unroll
                        for (int b = 0; b < 4; ++b)
                            gacc[a][b] += ai[a] * aj[b];
                }
#pragma unroll
                for (int a = 0; a < 4; ++a) {
                    int i = i0 + a;
                    int base = i * 15 - (i * (i - 1)) / 2 - i - 1;
#pragma unroll
                    for (int b = 0; b < 4; ++b)
                        cv2[(base + j0 + b) * CV_S + r] = gacc[a][b] * 0.1f;
                }
            } else {
                // diagonal 4x4 block: 6 upper pairs
                const int i0 = (q - 6) << 2;
                float g01 = 0.f, g02 = 0.f, g03 = 0.f,
                      g12 = 0.f, g13 = 0.f, g23 = 0.f;
#pragma unroll
                for (int d = 0; d < 10; ++d) {
                    float4 vi = *reinterpret_cast<const float4*>(wr + d * 16 + i0);
                    float a0 = vi.x, a1 = vi.y, a2 = vi.z, a3 = vi.w;
                    g01 += a0 * a1; g02 += a0 * a2; g03 += a0 * a3;
                    g12 += a1 * a2; g13 += a1 * a3; g23 += a2 * a3;
                }
                cv2[pair_idx(i0 + 0, i0 + 1) * CV_S + r] = g01 * 0.1f;
                cv2[pair_idx(i0 + 0, i0 + 2) * CV_S + r] = g02 * 0.1f;
                cv2[pair_idx(i0 + 0, i0 + 3) * CV_S + r] = g03 * 0.1f;
                cv2[pair_idx(i0 + 1, i0 + 2) * CV_S + r] = g12 * 0.1f;
                cv2[pair_idx(i0 + 1, i0 + 3) * CV_S + r] = g13 * 0.1f;
                cv2[pair_idx(i0 + 2, i0 + 3) * CV_S + r] = g23 * 0.1f;
            }
        } else if (t >= 256) {
            const int lane = t - 256;                 // 0..63
            const int r = lane & 15;
            const int c0 = (lane >> 4) << 2;          // 0,4,8,12
            const float* wr = win + r * WSTRIDE + c0;
            float sm[4], sq[4], dec[4], first[4], last[4];
#pragma unroll
            for (int k = 0; k < 4; ++k) { sm[k] = 0.f; sq[k] = 0.f; dec[k] = 0.f; }
#pragma unroll
            for (int d = 0; d < 10; ++d) {
                float4 v = *reinterpret_cast<const float4*>(wr + d * 16);
                float a[4] = {v.x, v.y, v.z, v.w};
#pragma unroll
                for (int k = 0; k < 4; ++k) {
                    sm[k] += a[k];
                    sq[k] += a[k] * a[k];
                    dec[k] += a[k] * (float)(d + 1);
                    if (d == 0) first[k] = a[k];
                    if (d == 9) last[k]  = a[k];
                }
            }
#pragma unroll
            for (int k = 0; k < 4; ++k) {
                int ch = c0 + k;
                float m = sm[k] * 0.1f;
                float var = fmaxf(sq[k] * 0.1f - m * m, 0.f);
                float s = sqrtf(var);
                featB[(0 * 16 + ch) * FB_S + r] = s;                       // std
                featB[(1 * 16 + ch) * FB_S + r] = m / (s + EPS_F);         // zscore
                featB[(2 * 16 + ch) * FB_S + r] = last[k] / first[k] - 1.f;// ret
                featB[(3 * 16 + ch) * FB_S + r] = dec[k] * (1.f / 55.f);   // decay
                featB[(4 * 16 + ch) * FB_S + r] = m;                       // mean
            }
        }
        __syncthreads();

        // ---- phase 3: outputs / accumulation (channel-per-thread) ----
#pragma unroll
        for (int rb4 = 0; rb4 < 4; ++rb4) {
            const int rb = rb4 * 4;
            float vals[4];
            if (c < 240) {
                float4 g4  = *reinterpret_cast<const float4*>(cv2 + pp * CV_S + rb);
                float4 mi4 = *reinterpret_cast<const float4*>(featB + (64 + pi) * FB_S + rb);
                float4 mj4 = *reinterpret_cast<const float4*>(featB + (64 + pj) * FB_S + rb);
                float g[4]  = {g4.x, g4.y, g4.z, g4.w};
                float mi[4] = {mi4.x, mi4.y, mi4.z, mi4.w};
                float mj[4] = {mj4.x, mj4.y, mj4.z, mj4.w};
                if (c < 120) {
                    float4 si4 = *reinterpret_cast<const float4*>(featB + pi * FB_S + rb);
                    float4 sj4 = *reinterpret_cast<const float4*>(featB + pj * FB_S + rb);
                    float si[4] = {si4.x, si4.y, si4.z, si4.w};
                    float sj[4] = {sj4.x, sj4.y, sj4.z, sj4.w};
#pragma unroll
                    for (int k = 0; k < 4; ++k)
                        vals[k] = (g[k] - mi[k] * mj[k]) / (si[k] * sj[k] + EPS_F);
                } else {
#pragma unroll
                    for (int k = 0; k < 4; ++k)
                        vals[k] = g[k] - mi[k] * mj[k];
                }
            } else {
                float4 f4 = *reinterpret_cast<const float4*>(featB + c2 * FB_S + rb);
                vals[0] = f4.x; vals[1] = f4.y; vals[2] = f4.z; vals[3] = f4.w;
            }
#pragma unroll
            for (int k = 0; k < 4; ++k) {
                if (MODE == 1) {
                    dst[(size_t)tile * (R_ * OUTC) + (rb + k) * OUTC + c]
                        = vals[k] * scale + shift;
                } else {
                    acc += vals[k];
                    acc2 += vals[k] * vals[k];
                }
            }
        }
    }

    if (MODE == 0) {
        dst[(size_t)blockIdx.x * 640 + t]        = acc;
        dst[(size_t)blockIdx.x * 640 + OUTC + t] = acc2;
    }
}

// Stage-A reduce: 768 blocks; block b sums rows {b + 768*j} of part1[nb][640]
// into part2[b][640]. Row reads coalesced (lanes = consecutive v).
__global__ __launch_bounds__(256)
void reduceA_kernel(const float* __restrict__ part1, float* __restrict__ part2,
                    int nb) {
    const int rows = nb / RA_BLOCKS;            // 16 (or 2 in fallback)
    const int b = blockIdx.x;
    for (int v = threadIdx.x; v < 640; v += 256) {
        float s = 0.f;
        for (int j = 0; j < rows; ++j)
            s += part1[(size_t)(b + RA_BLOCKS * j) * 640 + v];
        part2[(size_t)b * 640 + v] = s;
    }
}

// Final: 320 blocks (one per channel). fp64 column reduce of part2[768][640]
// (1.9 MB -> L2-resident, column reads cheap) with fixed LDS tree.
__global__ __launch_bounds__(256)
void finalize_kernel(const float* __restrict__ part2,
                     const float* __restrict__ gamma,
                     const float* __restrict__ beta,
                     float* __restrict__ ab) {
    __shared__ double rs[256], rs2[256];
    const int c = blockIdx.x, t = threadIdx.x;
    double s = 0.0, s2 = 0.0;
    for (int r = t; r < RA_BLOCKS; r += 256) {
        s  += (double)part2[(size_t)r * 640 + c];
        s2 += (double)part2[(size_t)r * 640 + c + OUTC];
    }
    rs[t] = s; rs2[t] = s2;
    __syncthreads();
    for (int off = 128; off; off >>= 1) {
        if (t < off) { rs[t] += rs[t + off]; rs2[t] += rs2[t + off]; }
        __syncthreads();
    }
    if (t == 0) {
        const double invN = 1.0 / (double)NROWS;
        double m = rs[0] * invN;
        double v = rs2[0] * invN - m * m;
        if (v < 0.0) v = 0.0;
        float a = gamma[c] / sqrtf((float)v + EPS_BN);
        ab[c] = a;
        ab[OUTC + c] = beta[c] - (float)m * a;
    }
}

extern "C" void kernel_launch(void* const* d_in, const int* in_sizes, int n_in,
                              void* d_out, int out_size, void* d_ws, size_t ws_size,
                              hipStream_t stream) {
    const float* x     = (const float*)d_in[0];
    const float* gamma = (const float*)d_in[1];
    const float* beta  = (const float*)d_in[2];
    float* out = (float*)d_out;

    // Prefer 1 tile/block for stats (12288 partial rows = 31.5 MB in ws);
    // compile-time fallback to 8 tiles/block if ws is small. ws_size is
    // fixed across calls -> same path every call (deterministic).
    const size_t need1 = (size_t)NTILES_TOTAL * 640 * 4
                       + (size_t)RA_BLOCKS * 640 * 4 + 640 * 4;
    const int nb = (need1 <= ws_size) ? NTILES_TOTAL : (NTILES_TOTAL / 8);

    float* part1 = (float*)d_ws;                       // nb*640 floats
    float* part2 = part1 + (size_t)nb * 640;           // 768*640 floats
    float* ab    = part2 + (size_t)RA_BLOCKS * 640;    // 640 floats

    if (nb == NTILES_TOTAL)
        fe_kernel<0, 1><<<nb, 320, 0, stream>>>(x, part1, nullptr);
    else
        fe_kernel<0, 8><<<nb, 320, 0, stream>>>(x, part1, nullptr);
    reduceA_kernel<<<RA_BLOCKS, 256, 0, stream>>>(part1, part2, nb);
    finalize_kernel<<<OUTC, 256, 0, stream>>>(part2, gamma, beta, ab);
    fe_kernel<1, 1><<<NTILES_TOTAL, 320, 0, stream>>>(x, out, ab);
}